// Round 10
// baseline (57.385 us; speedup 1.0000x reference)
//
#include <hip/hip_runtime.h>

#define HH 1024
#define WW 1024
#define BB 8

typedef float v4f __attribute__((ext_vector_type(4)));

__global__ __launch_bounds__(256) void getaffs_kernel(const float* __restrict__ seg,
                                                      float* __restrict__ out) {
    // Image-per-XCD swizzle (R3's winner) + 4 rows per block, store loop
    // plane-outer so each block writes 16 KB contiguous per plane (4x longer
    // NT bursts than R3, identical traffic and instruction counts).
    const int bid = blockIdx.x;
    const int b  = bid & 7;             // image == XCD
    const int rg = bid >> 3;            // row-group 0..255
    const int i0 = rg << 2;             // rows i0..i0+3
    const int j = threadIdx.x << 2;     // columns j..j+3

    const float* img = seg + (size_t)b * HH * WW;
    const size_t plane = (size_t)BB * HH * WW;
    float* outb = out + (size_t)b * HH * WW;

    v4f c[4];
    #pragma unroll
    for (int rr = 0; rr < 4; ++rr)
        c[rr] = *reinterpret_cast<const v4f*>(img + (size_t)(i0 + rr) * WW + j);

    const int ds[4] = {1, 3, 9, 27};

    // Row-offset planes 0,2,4,6: shifted row i-d (reg-reuse when in-group).
    #pragma unroll
    for (int k = 0; k < 4; ++k) {
        const int d = ds[k];
        float* po = outb + (size_t)(2 * k) * plane;
        #pragma unroll
        for (int rr = 0; rr < 4; ++rr) {
            const int i = i0 + rr;
            v4f r;
            if (rr - d >= 0) {
                r = c[rr - d];                       // static: d=1 rr>=1, d=3 rr==3
            } else if (i - d >= 0) {
                r = *reinterpret_cast<const v4f*>(img + (size_t)(i - d) * WW + j);
            } else {
                r = (v4f){0.f, 0.f, 0.f, 0.f};
            }
            v4f o;
            o.x = (r.x == c[rr].x) ? 1.f : 0.f;
            o.y = (r.y == c[rr].y) ? 1.f : 0.f;
            o.z = (r.z == c[rr].z) ? 1.f : 0.f;
            o.w = (r.w == c[rr].w) ? 1.f : 0.f;
            __builtin_nontemporal_store(o, reinterpret_cast<v4f*>(po + (size_t)i * WW + j));
        }
    }

    // Col-offset planes 1,3,5,7: unaligned vector load j-d, edge fallback j<d.
    #pragma unroll
    for (int k = 0; k < 4; ++k) {
        const int d = ds[k];
        float* po = outb + (size_t)(2 * k + 1) * plane;
        #pragma unroll
        for (int rr = 0; rr < 4; ++rr) {
            const int i = i0 + rr;
            const float* srow = img + (size_t)i * WW;
            v4f o;
            if (j >= d) {
                const v4f s = *reinterpret_cast<const v4f*>(srow + (j - d));
                o.x = (s.x == c[rr].x) ? 1.f : 0.f;
                o.y = (s.y == c[rr].y) ? 1.f : 0.f;
                o.z = (s.z == c[rr].z) ? 1.f : 0.f;
                o.w = (s.w == c[rr].w) ? 1.f : 0.f;
            } else {
                #pragma unroll
                for (int t = 0; t < 4; ++t) {
                    const int col = j + t - d;
                    const float v = (col >= 0) ? srow[col] : 0.f;
                    o[t] = (v == c[rr][t]) ? 1.f : 0.f;
                }
            }
            __builtin_nontemporal_store(o, reinterpret_cast<v4f*>(po + (size_t)i * WW + j));
        }
    }
}

extern "C" void kernel_launch(void* const* d_in, const int* in_sizes, int n_in,
                              void* d_out, int out_size, void* d_ws, size_t ws_size,
                              hipStream_t stream) {
    const float* seg = (const float*)d_in[0];
    float* out = (float*)d_out;
    dim3 grid(BB * (HH / 4));       // 2048: image x 4-row group
    dim3 block(WW / 4);
    getaffs_kernel<<<grid, block, 0, stream>>>(seg, out);
}